// Round 9
// baseline (290.300 us; speedup 1.0000x reference)
//
#include <hip/hip_runtime.h>
#include <hip/hip_bf16.h>

#define H_   16
#define D_   64
#define HID  1024
#define S_   2048
#define B_   2
#define M_   (B_*S_)
#define ROT  32
#define LOG2E 1.44269504088896341f
#define QSCALE (0.125f * LOG2E)

typedef __bf16 bf16x8 __attribute__((ext_vector_type(8)));
typedef float  f32x4  __attribute__((ext_vector_type(4)));

// ---- workspace layout (bytes) — round-5 proven map, no overlays ----
#define XB_OFF   0u                       // Xb bf16 [4096][1024]           8 MiB
#define WQT_OFF  (8u<<20)                 // Wq^T bf16 (QKV contiguous)     2 MiB
#define WKT_OFF  (10u<<20)
#define WVT_OFF  (12u<<20)
#define WOT_OFF  (14u<<20)
#define F_OFF    (16u<<20)                // rotary factors f32 [B][S][32]  512 KiB
#define QH_OFF   ((16u<<20) + (1u<<19))   // Q bf16 [B][H][S][D]            8 MiB
#define KH_OFF   (QH_OFF + (8u<<20))      // K bf16 [B][H][S][D]            8 MiB
#define VT_OFF   (KH_OFF + (8u<<20))      // V bf16 [B][H][D][S] (k-permuted tiles) 8 MiB
#define AB_OFF   (VT_OFF + (8u<<20))      // attn out bf16 [4096][1024]     8 MiB

__device__ __forceinline__ float fexp2(float x) {
#if __has_builtin(__builtin_amdgcn_exp2f)
  return __builtin_amdgcn_exp2f(x);
#else
  return __expf(x * 0.69314718055994531f);
#endif
}

__device__ __forceinline__ unsigned pk2(float a, float b) {
  union { unsigned u; __bf16 h[2]; } w;
  w.h[0] = (__bf16)a; w.h[1] = (__bf16)b;
  return w.u;
}

// ---------------- fused prep: convx | rotf | wtrans | biaschk ----------------
// flat grid: [0,4096) convx, [4096,4608) rotf, [4608,8704) wtrans, [8704,10752) biaschk
__global__ __launch_bounds__(256) void prep_kernel(const float* __restrict__ x,
                                                   const float* __restrict__ sinu,
                                                   const float* __restrict__ abias,
                                                   const float* __restrict__ W0, const float* __restrict__ W1,
                                                   const float* __restrict__ W2, const float* __restrict__ W3,
                                                   __hip_bfloat16* __restrict__ xb,
                                                   float* __restrict__ F,
                                                   __hip_bfloat16* __restrict__ T0, __hip_bfloat16* __restrict__ T1,
                                                   __hip_bfloat16* __restrict__ T2, __hip_bfloat16* __restrict__ T3,
                                                   int* __restrict__ flag) {
  __shared__ float tile[32][33];
  int idx = blockIdx.x;
  int tid = threadIdx.x;
  if (idx < 4096) {                       // ---- convx: x f32 -> bf16
    int i = (idx * 256 + tid) * 4;
    float4 v = *(const float4*)(x + i);
    union { __hip_bfloat16 h[4]; uint2 u; } o;
    o.h[0] = __float2bfloat16(v.x);
    o.h[1] = __float2bfloat16(v.y);
    o.h[2] = __float2bfloat16(v.z);
    o.h[3] = __float2bfloat16(v.w);
    *(uint2*)(xb + i) = o.u;
  } else if (idx < 4608) {                // ---- rotf: F = cos + (d odd ? sin : -sin)
    int i = (idx - 4096) * 256 + tid;
    int d  = i & (ROT-1);
    int bs = i >> 5;
    int s  = bs & (S_-1);
    int b  = bs >> 11;
    float sn = sinu[(((size_t)b*2 + 0)*S_ + s)*ROT + d];
    float cs = sinu[(((size_t)b*2 + 1)*S_ + s)*ROT + d];
    F[i] = cs + ((d & 1) ? sn : -sn);
  } else if (idx < 8704) {                // ---- wtrans: W[k][n] f32 -> Wt[n][k] bf16
    int widx = idx - 4608;
    int z    = widx >> 10;
    int rem  = widx & 1023;
    const float* W = (z==0) ? W0 : (z==1) ? W1 : (z==2) ? W2 : W3;
    __hip_bfloat16* T = (z==0) ? T0 : (z==1) ? T1 : (z==2) ? T2 : T3;
    int bx = (rem & 31) * 32;
    int by = (rem >> 5) * 32;
    int tx = tid & 31, ty = tid >> 5;
    #pragma unroll
    for (int i = 0; i < 4; i++)
      tile[ty + i*8][tx] = W[(size_t)(by + ty + i*8)*HID + bx + tx];
    __syncthreads();
    #pragma unroll
    for (int i = 0; i < 4; i++)
      T[(size_t)(bx + ty + i*8)*HID + by + tx] = __float2bfloat16(tile[tx][ty + i*8]);
  } else {                                // ---- biaschk: OR all bias bits
    size_t i = ((size_t)(idx - 8704) * 256 + tid) * 16;
    const uint4* p = (const uint4*)(abias + i);
    unsigned acc = 0;
    #pragma unroll
    for (int j = 0; j < 4; j++) {
      uint4 u = p[j];
      acc |= u.x | u.y | u.z | u.w;
    }
    if (acc) *flag = 1;
  }
}

// ---------------- m97-style 128x128 GEMM, fused QKV epilogue (round-6, proven ~43us) ----------------
__global__ __launch_bounds__(256) void qkv_kernel(const __hip_bfloat16* __restrict__ A,
                                                  const __hip_bfloat16* __restrict__ Bt,
                                                  const float* __restrict__ bq,
                                                  const float* __restrict__ bk,
                                                  const float* __restrict__ bv,
                                                  const float* __restrict__ F,
                                                  __hip_bfloat16* __restrict__ Qh,
                                                  __hip_bfloat16* __restrict__ Kh,
                                                  __hip_bfloat16* __restrict__ Vt) {
  __shared__ __align__(16) __bf16 Asm[2][128*32];
  __shared__ __align__(16) __bf16 Bsm[2][128*32];
  int tid  = threadIdx.x;
  int lane = tid & 63;
  int wv   = tid >> 6;
  int lr   = lane & 15;
  int qd   = lane >> 4;
  int row0 = blockIdx.y * 128;
  int col0 = blockIdx.x * 128;
  int wrow = (wv >> 1) * 64;
  int wcol = (wv & 1) * 64;

  int cg = ((tid & 3) ^ ((tid >> 2) & 3)) * 8;
  const __bf16* Ag = (const __bf16*)A  + (size_t)(row0 + (tid >> 2)) * HID + cg;
  const __bf16* Bg = (const __bf16*)Bt + (size_t)(col0 + (tid >> 2)) * HID + cg;

  f32x4 acc[4][4] = {};

  auto stage = [&](int buf, int k0) {
    __builtin_amdgcn_global_load_lds(Ag + k0,                  &Asm[buf][wv*512],        16, 0, 0);
    __builtin_amdgcn_global_load_lds(Ag + (size_t)64*HID + k0, &Asm[buf][2048 + wv*512], 16, 0, 0);
    __builtin_amdgcn_global_load_lds(Bg + k0,                  &Bsm[buf][wv*512],        16, 0, 0);
    __builtin_amdgcn_global_load_lds(Bg + (size_t)64*HID + k0, &Bsm[buf][2048 + wv*512], 16, 0, 0);
  };

  stage(0, 0);
  int buf = 0;
  for (int k0 = 0; k0 < HID; k0 += 32, buf ^= 1) {
    __syncthreads();
    if (k0 + 32 < HID) stage(buf ^ 1, k0 + 32);
    const __bf16* As = &Asm[buf][0];
    const __bf16* Bs = &Bsm[buf][0];
    bf16x8 a[4], b[4];
    #pragma unroll
    for (int i = 0; i < 4; i++) {
      int row = wrow + i*16 + lr;
      a[i] = *(const bf16x8*)(As + row*32 + ((qd ^ (row & 3)) * 8));
    }
    #pragma unroll
    for (int t = 0; t < 4; t++) {
      int row = wcol + t*16 + lr;
      b[t] = *(const bf16x8*)(Bs + row*32 + ((qd ^ (row & 3)) * 8));
    }
    #pragma unroll
    for (int i = 0; i < 4; i++)
      #pragma unroll
      for (int t = 0; t < 4; t++)
        acc[i][t] = __builtin_amdgcn_mfma_f32_16x16x32_bf16(a[i], b[t], acc[i][t], 0, 0, 0);
  }

  int proj = col0 >> 10;
  int nb   = (col0 & 1023) + wcol;
  const float* bias = (proj == 0) ? bq : ((proj == 1) ? bk : bv);
  #pragma unroll
  for (int i = 0; i < 4; i++) {
    #pragma unroll
    for (int t = 0; t < 4; t++) {
      int nl = nb + t*16 + lr;
      int h  = nl >> 6, d = nl & 63;
      if (proj == 2) {
        int m0 = row0 + wrow + i*16 + qd*4;
        int b2 = m0 >> 11, s0 = m0 & (S_-1);
        union { uint2 u; __bf16 hh[4]; } w;
        #pragma unroll
        for (int r = 0; r < 4; r++)
          w.hh[r] = (__bf16)(acc[i][t][r] + bias[nl]);
        // k-permuted store within each 64-wide s-tile: position 8m+j holds
        // k = 4m + (j&3) + 16*(j>>2)  (per 32-half). This makes the flash PV
        // B-operand equal to the lane's own packed scores (no P LDS round-trip).
        int pos = (s0 & ~31) | ((s0 & 12) << 1) | ((s0 >> 2) & 4);
        *(uint2*)((__bf16*)Vt + ((size_t)(b2*H_ + h)*D_ + d)*S_ + pos) = w.u;
      } else {
        __hip_bfloat16* dst = (proj == 0) ? Qh : Kh;
        #pragma unroll
        for (int r = 0; r < 4; r++) {
          int m = row0 + wrow + i*16 + qd*4 + r;
          int b2 = m >> 11, s = m & (S_-1);
          float v = acc[i][t][r] + bias[nl];
          if (d < ROT) v *= F[(size_t)(b2*S_ + s)*ROT + d];
          if (proj == 0) v *= QSCALE;
          dst[((size_t)(b2*H_ + h)*S_ + s)*D_ + d] = __float2bfloat16(v);
        }
      }
    }
  }
}

// ---------------- out-proj GEMM: 128x64 tiles (2 blocks/CU), f32 out ----------------
__global__ __launch_bounds__(256) void gemm_o64(const __hip_bfloat16* __restrict__ A,
                                                const __hip_bfloat16* __restrict__ Bt,
                                                float* __restrict__ outf) {
  __shared__ __align__(16) __bf16 Asm[2][128*32];
  __shared__ __align__(16) __bf16 Bsm[2][64*32];
  int tid  = threadIdx.x;
  int lane = tid & 63;
  int wv   = tid >> 6;
  int lr   = lane & 15;
  int qd   = lane >> 4;
  int row0 = blockIdx.y * 128;
  int col0 = blockIdx.x * 64;
  int cg = ((tid & 3) ^ ((tid >> 2) & 3)) * 8;
  const __bf16* Ag = (const __bf16*)A  + (size_t)(row0 + (tid >> 2)) * HID + cg;
  const __bf16* Bg = (const __bf16*)Bt + (size_t)(col0 + (tid >> 2)) * HID + cg;

  f32x4 acc[2][4] = {};
  auto stage = [&](int buf, int k0) {
    __builtin_amdgcn_global_load_lds(Ag + k0,                  &Asm[buf][wv*512],        16, 0, 0);
    __builtin_amdgcn_global_load_lds(Ag + (size_t)64*HID + k0, &Asm[buf][2048 + wv*512], 16, 0, 0);
    __builtin_amdgcn_global_load_lds(Bg + k0,                  &Bsm[buf][wv*512],        16, 0, 0);
  };
  stage(0, 0);
  int buf = 0;
  for (int k0 = 0; k0 < HID; k0 += 32, buf ^= 1) {
    __syncthreads();
    if (k0 + 32 < HID) stage(buf ^ 1, k0 + 32);
    const __bf16* As = &Asm[buf][0];
    const __bf16* Bs = &Bsm[buf][0];
    bf16x8 a[2], b[4];
    #pragma unroll
    for (int i = 0; i < 2; i++) {
      int row = wv*32 + i*16 + lr;
      a[i] = *(const bf16x8*)(As + row*32 + ((qd ^ (row & 3)) * 8));
    }
    #pragma unroll
    for (int t = 0; t < 4; t++) {
      int row = t*16 + lr;
      b[t] = *(const bf16x8*)(Bs + row*32 + ((qd ^ (row & 3)) * 8));
    }
    #pragma unroll
    for (int i = 0; i < 2; i++)
      #pragma unroll
      for (int t = 0; t < 4; t++)
        acc[i][t] = __builtin_amdgcn_mfma_f32_16x16x32_bf16(a[i], b[t], acc[i][t], 0, 0, 0);
  }
  #pragma unroll
  for (int i = 0; i < 2; i++)
    #pragma unroll
    for (int t = 0; t < 4; t++)
      #pragma unroll
      for (int r = 0; r < 4; r++) {
        int m = row0 + wv*32 + i*16 + qd*4 + r;
        int n = col0 + t*16 + lr;
        outf[(size_t)m*HID + n] = acc[i][t][r];
      }
}

// ---------------- flash attention: zero-LDS, direct-from-L2 K/V ----------------
// Round 9: K+V working set per XCD = 4 bh x 512 KB = 2 MiB, L2-resident. LDS staging
// of L2-fit data was pure overhead (barrier + vmcnt(0) drain + 16 ds_reads/iter).
// Fragments load straight from global (the LDS XOR swizzles cancel exactly):
//   kf0[c] = K[kt+c*16+lr][qd*8..], kf1 +32;  vp0[t] = V[t*16+lr][kt+qd*8..], vp1 +32.
// No __syncthreads anywhere — waves free-run; PV(prev) register MFMAs cover K-load
// latency; V loads issued before QK land during QK+exp. In-register P (k-permuted Vt),
// one-behind PV, MFMA row-sum (lacc) unchanged from round 6.
__global__ __launch_bounds__(256) void flash_kernel(const __hip_bfloat16* __restrict__ Qh,
                                                    const __hip_bfloat16* __restrict__ Kh,
                                                    const __hip_bfloat16* __restrict__ Vt,
                                                    const float* __restrict__ abias,
                                                    const int* __restrict__ flag,
                                                    __hip_bfloat16* __restrict__ Ab) {
  int tid  = threadIdx.x;
  int lane = tid & 63;
  int wv   = tid >> 6;
  int lr   = lane & 15;
  int qd   = lane >> 4;
  int idx  = blockIdx.x;              // 0..511
  int xcd  = idx & 7;
  int slot = idx >> 3;                // 0..63
  int bh   = xcd * 4 + (slot >> 4);
  int qblk = slot & 15;
  int b  = bh >> 4;
  int h  = bh & 15;
  int q0 = qblk * 128 + wv * 32;

  const __bf16* Kbase = (const __bf16*)Kh + (size_t)bh*S_*D_;
  const __bf16* Vbase = (const __bf16*)Vt + (size_t)bh*D_*S_;

  const __bf16* Qp = (const __bf16*)Qh + ((size_t)bh*S_ + q0 + lr)*D_ + qd*8;
  bf16x8 qa00 = *(const bf16x8*)(Qp);
  bf16x8 qa01 = *(const bf16x8*)(Qp + 32);
  bf16x8 qa10 = *(const bf16x8*)(Qp + 16*D_);
  bf16x8 qa11 = *(const bf16x8*)(Qp + 16*D_ + 32);

  int hasbias = *flag;
  const float* bp0 = abias + (size_t)b*S_*S_ + (size_t)(q0 + lr)*S_;
  const float* bp1 = bp0 + (size_t)16*S_;

  f32x4 oacc0[4] = {}, oacc1[4] = {};
  f32x4 lacc0 = {}, lacc1 = {};       // row-sum accumulators (ones^T · P via MFMA)

  // all-ones bf16x8 A-operand for the row-sum MFMAs
  union { bf16x8 v; unsigned u[4]; } von;
  von.u[0] = von.u[1] = von.u[2] = von.u[3] = 0x3F803F80u;

  // persistent pipeline registers: P (bf16 fragments) and V frags of previous tile
  union Pu { bf16x8 v; unsigned u[4]; };
  Pu pb00 = {}, pb01 = {}, pb10 = {}, pb11 = {};
  bf16x8 vp0[4], vp1[4];

  // per-lane base pointers (row strides: K rows D_, V rows S_)
  const __bf16* Kl = Kbase + (size_t)lr*D_ + qd*8;   // + (kt + c*16)*D_ ; +32 for hi
  const __bf16* Vl = Vbase + (size_t)lr*S_ + qd*8;   // + t*16*S_ + kt   ; +32 for hi

  for (int kt = 0; kt < S_; kt += 64) {
    // --- K frags for current tile, direct from L2 (issue first) ---
    bf16x8 kf0[4], kf1[4];
    #pragma unroll
    for (int c = 0; c < 4; c++) {
      const __bf16* Kr = Kl + (size_t)(kt + c*16)*D_;
      kf0[c] = *(const bf16x8*)(Kr);
      kf1[c] = *(const bf16x8*)(Kr + 32);
    }

    // --- PV for previous tile: operands in registers, covers K-load latency ---
    if (kt > 0) {
      __builtin_amdgcn_s_setprio(1);
      #pragma unroll
      for (int t = 0; t < 4; t++) {
        oacc0[t] = __builtin_amdgcn_mfma_f32_16x16x32_bf16(vp0[t], pb00.v, oacc0[t], 0, 0, 0);
        oacc0[t] = __builtin_amdgcn_mfma_f32_16x16x32_bf16(vp1[t], pb01.v, oacc0[t], 0, 0, 0);
        oacc1[t] = __builtin_amdgcn_mfma_f32_16x16x32_bf16(vp0[t], pb10.v, oacc1[t], 0, 0, 0);
        oacc1[t] = __builtin_amdgcn_mfma_f32_16x16x32_bf16(vp1[t], pb11.v, oacc1[t], 0, 0, 0);
      }
      __builtin_amdgcn_s_setprio(0);
    }

    // --- V frags for current tile (consumed next iter; land during QK/exp) ---
    #pragma unroll
    for (int t = 0; t < 4; t++) {
      const __bf16* Vr = Vl + (size_t)(t*16)*S_ + kt;
      vp0[t] = *(const bf16x8*)(Vr);
      vp1[t] = *(const bf16x8*)(Vr + 32);
    }

    // --- scores for current tile ---
    f32x4 s0[4], s1[4];
    __builtin_amdgcn_s_setprio(1);
    #pragma unroll
    for (int c = 0; c < 4; c++) {
      f32x4 z = {};
      z     = __builtin_amdgcn_mfma_f32_16x16x32_bf16(kf0[c], qa00, z, 0, 0, 0);
      s0[c] = __builtin_amdgcn_mfma_f32_16x16x32_bf16(kf1[c], qa01, z, 0, 0, 0);
      f32x4 z2 = {};
      z2    = __builtin_amdgcn_mfma_f32_16x16x32_bf16(kf0[c], qa10, z2, 0, 0, 0);
      s1[c] = __builtin_amdgcn_mfma_f32_16x16x32_bf16(kf1[c], qa11, z2, 0, 0, 0);
    }
    __builtin_amdgcn_s_setprio(0);

    // --- bias (slow path only) ---
    if (hasbias) {
      #pragma unroll
      for (int c = 0; c < 4; c++) {
        float4 b0 = *(const float4*)(bp0 + kt + c*16 + qd*4);
        float4 b1 = *(const float4*)(bp1 + kt + c*16 + qd*4);
        s0[c][0] += b0.x*LOG2E; s0[c][1] += b0.y*LOG2E; s0[c][2] += b0.z*LOG2E; s0[c][3] += b0.w*LOG2E;
        s1[c][0] += b1.x*LOG2E; s1[c][1] += b1.y*LOG2E; s1[c][2] += b1.z*LOG2E; s1[c][3] += b1.w*LOG2E;
      }
    }

    // --- exp2 + pack into persistent PV B-fragments (consumed next iter) ---
    #pragma unroll
    for (int c = 0; c < 2; c++) {
      pb00.u[2*c]   = pk2(fexp2(s0[c][0]), fexp2(s0[c][1]));
      pb00.u[2*c+1] = pk2(fexp2(s0[c][2]), fexp2(s0[c][3]));
      pb10.u[2*c]   = pk2(fexp2(s1[c][0]), fexp2(s1[c][1]));
      pb10.u[2*c+1] = pk2(fexp2(s1[c][2]), fexp2(s1[c][3]));
    }
    #pragma unroll
    for (int c = 2; c < 4; c++) {
      pb01.u[2*(c-2)]   = pk2(fexp2(s0[c][0]), fexp2(s0[c][1]));
      pb01.u[2*(c-2)+1] = pk2(fexp2(s0[c][2]), fexp2(s0[c][3]));
      pb11.u[2*(c-2)]   = pk2(fexp2(s1[c][0]), fexp2(s1[c][1]));
      pb11.u[2*(c-2)+1] = pk2(fexp2(s1[c][2]), fexp2(s1[c][3]));
    }

    // --- row sums on the matrix pipe: lacc += ones^T · P(cur) ---
    lacc0 = __builtin_amdgcn_mfma_f32_16x16x32_bf16(von.v, pb00.v, lacc0, 0, 0, 0);
    lacc0 = __builtin_amdgcn_mfma_f32_16x16x32_bf16(von.v, pb01.v, lacc0, 0, 0, 0);
    lacc1 = __builtin_amdgcn_mfma_f32_16x16x32_bf16(von.v, pb10.v, lacc1, 0, 0, 0);
    lacc1 = __builtin_amdgcn_mfma_f32_16x16x32_bf16(von.v, pb11.v, lacc1, 0, 0, 0);
  }

  // --- final PV for the last tile (all operands in registers) ---
  __builtin_amdgcn_s_setprio(1);
  #pragma unroll
  for (int t = 0; t < 4; t++) {
    oacc0[t] = __builtin_amdgcn_mfma_f32_16x16x32_bf16(vp0[t], pb00.v, oacc0[t], 0, 0, 0);
    oacc0[t] = __builtin_amdgcn_mfma_f32_16x16x32_bf16(vp1[t], pb01.v, oacc0[t], 0, 0, 0);
    oacc1[t] = __builtin_amdgcn_mfma_f32_16x16x32_bf16(vp0[t], pb10.v, oacc1[t], 0, 0, 0);
    oacc1[t] = __builtin_amdgcn_mfma_f32_16x16x32_bf16(vp1[t], pb11.v, oacc1[t], 0, 0, 0);
  }
  __builtin_amdgcn_s_setprio(0);

  // lacc[r] holds the full row sum for q-row lr (replicated across r and qd)
  float inv0 = 1.0f / lacc0[0];
  float inv1 = 1.0f / lacc1[0];
  size_t ro0 = ((size_t)(b*S_ + q0 + lr))*HID + h*D_;
  size_t ro1 = ((size_t)(b*S_ + q0 + 16 + lr))*HID + h*D_;
  #pragma unroll
  for (int t = 0; t < 4; t++) {
    union { uint2 u; __bf16 hh[4]; } w0, w1;
    #pragma unroll
    for (int r = 0; r < 4; r++) {
      w0.hh[r] = (__bf16)(oacc0[t][r]*inv0);
      w1.hh[r] = (__bf16)(oacc1[t][r]*inv1);
    }
    *(uint2*)((__bf16*)Ab + ro0 + t*16 + qd*4) = w0.u;
    *(uint2*)((__bf16*)Ab + ro1 + t*16 + qd*4) = w1.u;
  }
}

extern "C" void kernel_launch(void* const* d_in, const int* in_sizes, int n_in,
                              void* d_out, int out_size, void* d_ws, size_t ws_size,
                              hipStream_t stream) {
  (void)in_sizes; (void)n_in; (void)out_size; (void)ws_size;
  const float* x     = (const float*)d_in[0];
  const float* sinu  = (const float*)d_in[1];
  const float* abias = (const float*)d_in[2];
  const float* Wq    = (const float*)d_in[3];
  const float* bq    = (const float*)d_in[4];
  const float* Wk    = (const float*)d_in[5];
  const float* bk    = (const float*)d_in[6];
  const float* Wv    = (const float*)d_in[7];
  const float* bv    = (const float*)d_in[8];
  const float* Wo    = (const float*)d_in[9];

  char* ws = (char*)d_ws;
  __hip_bfloat16* Xb  = (__hip_bfloat16*)(ws + XB_OFF);
  __hip_bfloat16* Wqt = (__hip_bfloat16*)(ws + WQT_OFF);
  __hip_bfloat16* Wkt = (__hip_bfloat16*)(ws + WKT_OFF);
  __hip_bfloat16* Wvt = (__hip_bfloat16*)(ws + WVT_OFF);
  __hip_bfloat16* Wot = (__hip_bfloat16*)(ws + WOT_OFF);
  float*          F   = (float*)(ws + F_OFF);
  __hip_bfloat16* Qh  = (__hip_bfloat16*)(ws + QH_OFF);
  __hip_bfloat16* Kh  = (__hip_bfloat16*)(ws + KH_OFF);
  __hip_bfloat16* Vt  = (__hip_bfloat16*)(ws + VT_OFF);
  __hip_bfloat16* Ab  = (__hip_bfloat16*)(ws + AB_OFF);
  int* flag = (int*)d_out;   // scratch; overwritten by the final GEMM

  hipMemsetAsync(flag, 0, 4, stream);
  prep_kernel<<<10752, 256, 0, stream>>>(x, sinu, abias, Wq, Wk, Wv, Wo,
                                         Xb, F, Wqt, Wkt, Wvt, Wot, flag);

  qkv_kernel<<<dim3(3*HID/128, M_/128), 256, 0, stream>>>(
      Xb, Wqt, bq, bk, bv, F, Qh, Kh, Vt);

  flash_kernel<<<dim3(512), 256, 0, stream>>>(Qh, Kh, Vt, abias, flag, Ab);

  gemm_o64<<<dim3(HID/64, M_/128), 256, 0, stream>>>(Ab, Wot, (float*)d_out);
}

// Round 11
// 218.418 us; speedup vs baseline: 1.3291x; 1.3291x over previous
//
#include <hip/hip_runtime.h>
#include <hip/hip_bf16.h>

#define H_   16
#define D_   64
#define HID  1024
#define S_   2048
#define B_   2
#define M_   (B_*S_)
#define ROT  32
#define LOG2E 1.44269504088896341f
#define QSCALE (0.125f * LOG2E)

typedef __bf16 bf16x8 __attribute__((ext_vector_type(8)));
typedef float  f32x4  __attribute__((ext_vector_type(4)));

// ---- workspace layout (bytes) — round-5 proven map, no overlays ----
#define XB_OFF   0u                       // Xb bf16 [4096][1024]           8 MiB
#define WQT_OFF  (8u<<20)                 // Wq^T bf16 (QKV contiguous)     2 MiB
#define WKT_OFF  (10u<<20)
#define WVT_OFF  (12u<<20)
#define WOT_OFF  (14u<<20)
#define F_OFF    (16u<<20)                // rotary factors f32 [B][S][32]  512 KiB
#define QH_OFF   ((16u<<20) + (1u<<19))   // Q bf16 [B][H][S][D]            8 MiB
#define KH_OFF   (QH_OFF + (8u<<20))      // K bf16 [B][H][S][D]            8 MiB
#define VT_OFF   (KH_OFF + (8u<<20))      // V bf16 [B][H][D][S] (k-permuted tiles) 8 MiB
#define AB_OFF   (VT_OFF + (8u<<20))      // attn out bf16 [4096][1024]     8 MiB

__device__ __forceinline__ float fexp2(float x) {
#if __has_builtin(__builtin_amdgcn_exp2f)
  return __builtin_amdgcn_exp2f(x);
#else
  return __expf(x * 0.69314718055994531f);
#endif
}

__device__ __forceinline__ unsigned pk2(float a, float b) {
  union { unsigned u; __bf16 h[2]; } w;
  w.h[0] = (__bf16)a; w.h[1] = (__bf16)b;
  return w.u;
}

// ---------------- fused prep: convx | rotf | wtrans | biaschk ----------------
// flat grid: [0,4096) convx, [4096,4608) rotf, [4608,8704) wtrans, [8704,10752) biaschk
__global__ __launch_bounds__(256) void prep_kernel(const float* __restrict__ x,
                                                   const float* __restrict__ sinu,
                                                   const float* __restrict__ abias,
                                                   const float* __restrict__ W0, const float* __restrict__ W1,
                                                   const float* __restrict__ W2, const float* __restrict__ W3,
                                                   __hip_bfloat16* __restrict__ xb,
                                                   float* __restrict__ F,
                                                   __hip_bfloat16* __restrict__ T0, __hip_bfloat16* __restrict__ T1,
                                                   __hip_bfloat16* __restrict__ T2, __hip_bfloat16* __restrict__ T3,
                                                   int* __restrict__ flag) {
  __shared__ float tile[32][33];
  int idx = blockIdx.x;
  int tid = threadIdx.x;
  if (idx < 4096) {                       // ---- convx: x f32 -> bf16
    int i = (idx * 256 + tid) * 4;
    float4 v = *(const float4*)(x + i);
    union { __hip_bfloat16 h[4]; uint2 u; } o;
    o.h[0] = __float2bfloat16(v.x);
    o.h[1] = __float2bfloat16(v.y);
    o.h[2] = __float2bfloat16(v.z);
    o.h[3] = __float2bfloat16(v.w);
    *(uint2*)(xb + i) = o.u;
  } else if (idx < 4608) {                // ---- rotf: F = cos + (d odd ? sin : -sin)
    int i = (idx - 4096) * 256 + tid;
    int d  = i & (ROT-1);
    int bs = i >> 5;
    int s  = bs & (S_-1);
    int b  = bs >> 11;
    float sn = sinu[(((size_t)b*2 + 0)*S_ + s)*ROT + d];
    float cs = sinu[(((size_t)b*2 + 1)*S_ + s)*ROT + d];
    F[i] = cs + ((d & 1) ? sn : -sn);
  } else if (idx < 8704) {                // ---- wtrans: W[k][n] f32 -> Wt[n][k] bf16
    int widx = idx - 4608;
    int z    = widx >> 10;
    int rem  = widx & 1023;
    const float* W = (z==0) ? W0 : (z==1) ? W1 : (z==2) ? W2 : W3;
    __hip_bfloat16* T = (z==0) ? T0 : (z==1) ? T1 : (z==2) ? T2 : T3;
    int bx = (rem & 31) * 32;
    int by = (rem >> 5) * 32;
    int tx = tid & 31, ty = tid >> 5;
    #pragma unroll
    for (int i = 0; i < 4; i++)
      tile[ty + i*8][tx] = W[(size_t)(by + ty + i*8)*HID + bx + tx];
    __syncthreads();
    #pragma unroll
    for (int i = 0; i < 4; i++)
      T[(size_t)(bx + ty + i*8)*HID + by + tx] = __float2bfloat16(tile[tx][ty + i*8]);
  } else {                                // ---- biaschk: OR all bias bits
    size_t i = ((size_t)(idx - 8704) * 256 + tid) * 16;
    const uint4* p = (const uint4*)(abias + i);
    unsigned acc = 0;
    #pragma unroll
    for (int j = 0; j < 4; j++) {
      uint4 u = p[j];
      acc |= u.x | u.y | u.z | u.w;
    }
    if (acc) *flag = 1;
  }
}

// ---------------- m97-style 128x128 GEMM, fused QKV epilogue (round-6, proven) ----------------
__global__ __launch_bounds__(256) void qkv_kernel(const __hip_bfloat16* __restrict__ A,
                                                  const __hip_bfloat16* __restrict__ Bt,
                                                  const float* __restrict__ bq,
                                                  const float* __restrict__ bk,
                                                  const float* __restrict__ bv,
                                                  const float* __restrict__ F,
                                                  __hip_bfloat16* __restrict__ Qh,
                                                  __hip_bfloat16* __restrict__ Kh,
                                                  __hip_bfloat16* __restrict__ Vt) {
  __shared__ __align__(16) __bf16 Asm[2][128*32];
  __shared__ __align__(16) __bf16 Bsm[2][128*32];
  int tid  = threadIdx.x;
  int lane = tid & 63;
  int wv   = tid >> 6;
  int lr   = lane & 15;
  int qd   = lane >> 4;
  int row0 = blockIdx.y * 128;
  int col0 = blockIdx.x * 128;
  int wrow = (wv >> 1) * 64;
  int wcol = (wv & 1) * 64;

  int cg = ((tid & 3) ^ ((tid >> 2) & 3)) * 8;
  const __bf16* Ag = (const __bf16*)A  + (size_t)(row0 + (tid >> 2)) * HID + cg;
  const __bf16* Bg = (const __bf16*)Bt + (size_t)(col0 + (tid >> 2)) * HID + cg;

  f32x4 acc[4][4] = {};

  auto stage = [&](int buf, int k0) {
    __builtin_amdgcn_global_load_lds(Ag + k0,                  &Asm[buf][wv*512],        16, 0, 0);
    __builtin_amdgcn_global_load_lds(Ag + (size_t)64*HID + k0, &Asm[buf][2048 + wv*512], 16, 0, 0);
    __builtin_amdgcn_global_load_lds(Bg + k0,                  &Bsm[buf][wv*512],        16, 0, 0);
    __builtin_amdgcn_global_load_lds(Bg + (size_t)64*HID + k0, &Bsm[buf][2048 + wv*512], 16, 0, 0);
  };

  stage(0, 0);
  int buf = 0;
  for (int k0 = 0; k0 < HID; k0 += 32, buf ^= 1) {
    __syncthreads();
    if (k0 + 32 < HID) stage(buf ^ 1, k0 + 32);
    const __bf16* As = &Asm[buf][0];
    const __bf16* Bs = &Bsm[buf][0];
    bf16x8 a[4], b[4];
    #pragma unroll
    for (int i = 0; i < 4; i++) {
      int row = wrow + i*16 + lr;
      a[i] = *(const bf16x8*)(As + row*32 + ((qd ^ (row & 3)) * 8));
    }
    #pragma unroll
    for (int t = 0; t < 4; t++) {
      int row = wcol + t*16 + lr;
      b[t] = *(const bf16x8*)(Bs + row*32 + ((qd ^ (row & 3)) * 8));
    }
    #pragma unroll
    for (int i = 0; i < 4; i++)
      #pragma unroll
      for (int t = 0; t < 4; t++)
        acc[i][t] = __builtin_amdgcn_mfma_f32_16x16x32_bf16(a[i], b[t], acc[i][t], 0, 0, 0);
  }

  int proj = col0 >> 10;
  int nb   = (col0 & 1023) + wcol;
  const float* bias = (proj == 0) ? bq : ((proj == 1) ? bk : bv);
  #pragma unroll
  for (int i = 0; i < 4; i++) {
    #pragma unroll
    for (int t = 0; t < 4; t++) {
      int nl = nb + t*16 + lr;
      int h  = nl >> 6, d = nl & 63;
      if (proj == 2) {
        int m0 = row0 + wrow + i*16 + qd*4;
        int b2 = m0 >> 11, s0 = m0 & (S_-1);
        union { uint2 u; __bf16 hh[4]; } w;
        #pragma unroll
        for (int r = 0; r < 4; r++)
          w.hh[r] = (__bf16)(acc[i][t][r] + bias[nl]);
        // k-permuted store within each 64-wide s-tile: position 8m+j holds
        // k = 4m + (j&3) + 16*(j>>2)  (per 32-half). This makes the flash PV
        // B-operand equal to the lane's own packed scores (no P LDS round-trip).
        int pos = (s0 & ~31) | ((s0 & 12) << 1) | ((s0 >> 2) & 4);
        *(uint2*)((__bf16*)Vt + ((size_t)(b2*H_ + h)*D_ + d)*S_ + pos) = w.u;
      } else {
        __hip_bfloat16* dst = (proj == 0) ? Qh : Kh;
        #pragma unroll
        for (int r = 0; r < 4; r++) {
          int m = row0 + wrow + i*16 + qd*4 + r;
          int b2 = m >> 11, s = m & (S_-1);
          float v = acc[i][t][r] + bias[nl];
          if (d < ROT) v *= F[(size_t)(b2*S_ + s)*ROT + d];
          if (proj == 0) v *= QSCALE;
          dst[((size_t)(b2*H_ + h)*S_ + s)*D_ + d] = __float2bfloat16(v);
        }
      }
    }
  }
}

// ---------------- out-proj GEMM: 128x64 tiles (2 blocks/CU), f32 out ----------------
__global__ __launch_bounds__(256) void gemm_o64(const __hip_bfloat16* __restrict__ A,
                                                const __hip_bfloat16* __restrict__ Bt,
                                                float* __restrict__ outf) {
  __shared__ __align__(16) __bf16 Asm[2][128*32];
  __shared__ __align__(16) __bf16 Bsm[2][64*32];
  int tid  = threadIdx.x;
  int lane = tid & 63;
  int wv   = tid >> 6;
  int lr   = lane & 15;
  int qd   = lane >> 4;
  int row0 = blockIdx.y * 128;
  int col0 = blockIdx.x * 64;
  int cg = ((tid & 3) ^ ((tid >> 2) & 3)) * 8;
  const __bf16* Ag = (const __bf16*)A  + (size_t)(row0 + (tid >> 2)) * HID + cg;
  const __bf16* Bg = (const __bf16*)Bt + (size_t)(col0 + (tid >> 2)) * HID + cg;

  f32x4 acc[2][4] = {};
  auto stage = [&](int buf, int k0) {
    __builtin_amdgcn_global_load_lds(Ag + k0,                  &Asm[buf][wv*512],        16, 0, 0);
    __builtin_amdgcn_global_load_lds(Ag + (size_t)64*HID + k0, &Asm[buf][2048 + wv*512], 16, 0, 0);
    __builtin_amdgcn_global_load_lds(Bg + k0,                  &Bsm[buf][wv*512],        16, 0, 0);
  };
  stage(0, 0);
  int buf = 0;
  for (int k0 = 0; k0 < HID; k0 += 32, buf ^= 1) {
    __syncthreads();
    if (k0 + 32 < HID) stage(buf ^ 1, k0 + 32);
    const __bf16* As = &Asm[buf][0];
    const __bf16* Bs = &Bsm[buf][0];
    bf16x8 a[2], b[4];
    #pragma unroll
    for (int i = 0; i < 2; i++) {
      int row = wv*32 + i*16 + lr;
      a[i] = *(const bf16x8*)(As + row*32 + ((qd ^ (row & 3)) * 8));
    }
    #pragma unroll
    for (int t = 0; t < 4; t++) {
      int row = t*16 + lr;
      b[t] = *(const bf16x8*)(Bs + row*32 + ((qd ^ (row & 3)) * 8));
    }
    #pragma unroll
    for (int i = 0; i < 2; i++)
      #pragma unroll
      for (int t = 0; t < 4; t++)
        acc[i][t] = __builtin_amdgcn_mfma_f32_16x16x32_bf16(a[i], b[t], acc[i][t], 0, 0, 0);
  }
  #pragma unroll
  for (int i = 0; i < 2; i++)
    #pragma unroll
    for (int t = 0; t < 4; t++)
      #pragma unroll
      for (int r = 0; r < 4; r++) {
        int m = row0 + wv*32 + i*16 + qd*4 + r;
        int n = col0 + t*16 + lr;
        outf[(size_t)m*HID + n] = acc[i][t][r];
      }
}

// ---------------- flash attention: in-register P + one-behind PV (round-6, proven) ----------------
// Swapped QK^T leaves lane (lr,qd) holding P[q=lr][k=16c+4qd+r]. Vt's column order is
// permuted (position 8m+j holds k=4m+(j&3)+16*(j>>2) per 32-half), so the PV B-operand
// is the lane's own exp'd scores packed to bf16 — no P LDS, no cross-lane traffic.
// PV for tile i-1 is issued at the TOP of iteration i from persistent registers.
// lsum via MFMA — lacc = mfma(ones, pb, lacc) sums rows of P on the matrix pipe.
// Round 10/11: V-frag ds_reads hoisted to just after PV(prev) so their latency drains
// under the QK^T MFMAs + exp chain instead of at the tail of the body.
__global__ __launch_bounds__(256) void flash_kernel(const __hip_bfloat16* __restrict__ Qh,
                                                    const __hip_bfloat16* __restrict__ Kh,
                                                    const __hip_bfloat16* __restrict__ Vt,
                                                    const float* __restrict__ abias,
                                                    const int* __restrict__ flag,
                                                    __hip_bfloat16* __restrict__ Ab) {
  __shared__ __align__(16) __bf16 Ksm[2][64*64];
  __shared__ __align__(16) __bf16 Vsm[2][64*64];
  int tid  = threadIdx.x;
  int lane = tid & 63;
  int wv   = tid >> 6;
  int lr   = lane & 15;
  int qd   = lane >> 4;
  int idx  = blockIdx.x;              // 0..511
  int xcd  = idx & 7;
  int slot = idx >> 3;                // 0..63
  int bh   = xcd * 4 + (slot >> 4);
  int qblk = slot & 15;
  int b  = bh >> 4;
  int h  = bh & 15;
  int q0 = qblk * 128 + wv * 32;

  const __bf16* Kbase = (const __bf16*)Kh + (size_t)bh*S_*D_;
  const __bf16* Vbase = (const __bf16*)Vt + (size_t)bh*D_*S_;

  const __bf16* Qp = (const __bf16*)Qh + ((size_t)bh*S_ + q0 + lr)*D_ + qd*8;
  bf16x8 qa00 = *(const bf16x8*)(Qp);
  bf16x8 qa01 = *(const bf16x8*)(Qp + 32);
  bf16x8 qa10 = *(const bf16x8*)(Qp + 16*D_);
  bf16x8 qa11 = *(const bf16x8*)(Qp + 16*D_ + 32);

  int hasbias = *flag;
  const float* bp0 = abias + (size_t)b*S_*S_ + (size_t)(q0 + lr)*S_;
  const float* bp1 = bp0 + (size_t)16*S_;

  int rowb = tid >> 3;
  int cg8  = ((tid & 7) ^ (rowb & 7)) * 8;

  auto stageKV = [&](int bf, int kt2) {
    __builtin_amdgcn_global_load_lds(Kbase + (size_t)(kt2 + rowb)*D_ + cg8,      &Ksm[bf][wv*512],        16, 0, 0);
    __builtin_amdgcn_global_load_lds(Kbase + (size_t)(kt2 + 32 + rowb)*D_ + cg8, &Ksm[bf][2048 + wv*512], 16, 0, 0);
    __builtin_amdgcn_global_load_lds(Vbase + (size_t)rowb*S_ + kt2 + cg8,        &Vsm[bf][wv*512],        16, 0, 0);
    __builtin_amdgcn_global_load_lds(Vbase + (size_t)(32 + rowb)*S_ + kt2 + cg8, &Vsm[bf][2048 + wv*512], 16, 0, 0);
  };

  f32x4 oacc0[4] = {}, oacc1[4] = {};
  f32x4 lacc0 = {}, lacc1 = {};       // row-sum accumulators (ones^T · P via MFMA)
  int sw = lr & 7;

  // all-ones bf16x8 A-operand for the row-sum MFMAs
  union { bf16x8 v; unsigned u[4]; } von;
  von.u[0] = von.u[1] = von.u[2] = von.u[3] = 0x3F803F80u;

  // persistent pipeline registers: P (bf16 fragments) and V frags of previous tile
  union Pu { bf16x8 v; unsigned u[4]; };
  Pu pb00 = {}, pb01 = {}, pb10 = {}, pb11 = {};
  bf16x8 vp0[4], vp1[4];

  stageKV(0, 0);
  int buf = 0;
  for (int kt = 0; kt < S_; kt += 64, buf ^= 1) {
    __syncthreads();                   // staged buf ready
    if (kt + 64 < S_) stageKV(buf ^ 1, kt + 64);

    // --- K frags for current tile (issue early; PV below is independent) ---
    bf16x8 kf0[4], kf1[4];
    #pragma unroll
    for (int c = 0; c < 4; c++) {
      const __bf16* Kr = &Ksm[buf][(c*16 + lr)*64];
      kf0[c] = *(const bf16x8*)(Kr + ((qd       ^ sw) * 8));
      kf1[c] = *(const bf16x8*)(Kr + (((4 + qd) ^ sw) * 8));
    }

    // --- PV for previous tile: all operands in registers, no waits ---
    if (kt > 0) {
      __builtin_amdgcn_s_setprio(1);
      #pragma unroll
      for (int t = 0; t < 4; t++) {
        oacc0[t] = __builtin_amdgcn_mfma_f32_16x16x32_bf16(vp0[t], pb00.v, oacc0[t], 0, 0, 0);
        oacc0[t] = __builtin_amdgcn_mfma_f32_16x16x32_bf16(vp1[t], pb01.v, oacc0[t], 0, 0, 0);
        oacc1[t] = __builtin_amdgcn_mfma_f32_16x16x32_bf16(vp0[t], pb10.v, oacc1[t], 0, 0, 0);
        oacc1[t] = __builtin_amdgcn_mfma_f32_16x16x32_bf16(vp1[t], pb11.v, oacc1[t], 0, 0, 0);
      }
      __builtin_amdgcn_s_setprio(0);
    }

    // --- V frags (k-permuted layout) into persistent registers: issued early so the
    //     ds_read latency drains under QK^T + exp (consumed next iteration) ---
    #pragma unroll
    for (int t = 0; t < 4; t++) {
      const __bf16* Vr = &Vsm[buf][(t*16 + lr)*64];
      vp0[t] = *(const bf16x8*)(Vr + ((qd       ^ sw) * 8));
      vp1[t] = *(const bf16x8*)(Vr + (((4 + qd) ^ sw) * 8));
    }

    // --- scores for current tile ---
    f32x4 s0[4], s1[4];
    __builtin_amdgcn_s_setprio(1);
    #pragma unroll
    for (int c = 0; c < 4; c++) {
      f32x4 z = {};
      z     = __builtin_amdgcn_mfma_f32_16x16x32_bf16(kf0[c], qa00, z, 0, 0, 0);
      s0[c] = __builtin_amdgcn_mfma_f32_16x16x32_bf16(kf1[c], qa01, z, 0, 0, 0);
      f32x4 z2 = {};
      z2    = __builtin_amdgcn_mfma_f32_16x16x32_bf16(kf0[c], qa10, z2, 0, 0, 0);
      s1[c] = __builtin_amdgcn_mfma_f32_16x16x32_bf16(kf1[c], qa11, z2, 0, 0, 0);
    }
    __builtin_amdgcn_s_setprio(0);

    // --- bias (slow path only) ---
    if (hasbias) {
      #pragma unroll
      for (int c = 0; c < 4; c++) {
        float4 b0 = *(const float4*)(bp0 + kt + c*16 + qd*4);
        float4 b1 = *(const float4*)(bp1 + kt + c*16 + qd*4);
        s0[c][0] += b0.x*LOG2E; s0[c][1] += b0.y*LOG2E; s0[c][2] += b0.z*LOG2E; s0[c][3] += b0.w*LOG2E;
        s1[c][0] += b1.x*LOG2E; s1[c][1] += b1.y*LOG2E; s1[c][2] += b1.z*LOG2E; s1[c][3] += b1.w*LOG2E;
      }
    }

    // --- exp2 + pack into persistent PV B-fragments (consumed next iter) ---
    #pragma unroll
    for (int c = 0; c < 2; c++) {
      pb00.u[2*c]   = pk2(fexp2(s0[c][0]), fexp2(s0[c][1]));
      pb00.u[2*c+1] = pk2(fexp2(s0[c][2]), fexp2(s0[c][3]));
      pb10.u[2*c]   = pk2(fexp2(s1[c][0]), fexp2(s1[c][1]));
      pb10.u[2*c+1] = pk2(fexp2(s1[c][2]), fexp2(s1[c][3]));
    }
    #pragma unroll
    for (int c = 2; c < 4; c++) {
      pb01.u[2*(c-2)]   = pk2(fexp2(s0[c][0]), fexp2(s0[c][1]));
      pb01.u[2*(c-2)+1] = pk2(fexp2(s0[c][2]), fexp2(s0[c][3]));
      pb11.u[2*(c-2)]   = pk2(fexp2(s1[c][0]), fexp2(s1[c][1]));
      pb11.u[2*(c-2)+1] = pk2(fexp2(s1[c][2]), fexp2(s1[c][3]));
    }

    // --- row sums on the matrix pipe: lacc += ones^T · P(cur) ---
    lacc0 = __builtin_amdgcn_mfma_f32_16x16x32_bf16(von.v, pb00.v, lacc0, 0, 0, 0);
    lacc0 = __builtin_amdgcn_mfma_f32_16x16x32_bf16(von.v, pb01.v, lacc0, 0, 0, 0);
    lacc1 = __builtin_amdgcn_mfma_f32_16x16x32_bf16(von.v, pb10.v, lacc1, 0, 0, 0);
    lacc1 = __builtin_amdgcn_mfma_f32_16x16x32_bf16(von.v, pb11.v, lacc1, 0, 0, 0);
  }

  // --- final PV for the last tile (all operands in registers) ---
  __builtin_amdgcn_s_setprio(1);
  #pragma unroll
  for (int t = 0; t < 4; t++) {
    oacc0[t] = __builtin_amdgcn_mfma_f32_16x16x32_bf16(vp0[t], pb00.v, oacc0[t], 0, 0, 0);
    oacc0[t] = __builtin_amdgcn_mfma_f32_16x16x32_bf16(vp1[t], pb01.v, oacc0[t], 0, 0, 0);
    oacc1[t] = __builtin_amdgcn_mfma_f32_16x16x32_bf16(vp0[t], pb10.v, oacc1[t], 0, 0, 0);
    oacc1[t] = __builtin_amdgcn_mfma_f32_16x16x32_bf16(vp1[t], pb11.v, oacc1[t], 0, 0, 0);
  }
  __builtin_amdgcn_s_setprio(0);

  // lacc[r] holds the full row sum for q-row lr (replicated across r and qd)
  float inv0 = 1.0f / lacc0[0];
  float inv1 = 1.0f / lacc1[0];
  size_t ro0 = ((size_t)(b*S_ + q0 + lr))*HID + h*D_;
  size_t ro1 = ((size_t)(b*S_ + q0 + 16 + lr))*HID + h*D_;
  #pragma unroll
  for (int t = 0; t < 4; t++) {
    union { uint2 u; __bf16 hh[4]; } w0, w1;
    #pragma unroll
    for (int r = 0; r < 4; r++) {
      w0.hh[r] = (__bf16)(oacc0[t][r]*inv0);
      w1.hh[r] = (__bf16)(oacc1[t][r]*inv1);
    }
    *(uint2*)((__bf16*)Ab + ro0 + t*16 + qd*4) = w0.u;
    *(uint2*)((__bf16*)Ab + ro1 + t*16 + qd*4) = w1.u;
  }
}

extern "C" void kernel_launch(void* const* d_in, const int* in_sizes, int n_in,
                              void* d_out, int out_size, void* d_ws, size_t ws_size,
                              hipStream_t stream) {
  (void)in_sizes; (void)n_in; (void)out_size; (void)ws_size;
  const float* x     = (const float*)d_in[0];
  const float* sinu  = (const float*)d_in[1];
  const float* abias = (const float*)d_in[2];
  const float* Wq    = (const float*)d_in[3];
  const float* bq    = (const float*)d_in[4];
  const float* Wk    = (const float*)d_in[5];
  const float* bk    = (const float*)d_in[6];
  const float* Wv    = (const float*)d_in[7];
  const float* bv    = (const float*)d_in[8];
  const float* Wo    = (const float*)d_in[9];

  char* ws = (char*)d_ws;
  __hip_bfloat16* Xb  = (__hip_bfloat16*)(ws + XB_OFF);
  __hip_bfloat16* Wqt = (__hip_bfloat16*)(ws + WQT_OFF);
  __hip_bfloat16* Wkt = (__hip_bfloat16*)(ws + WKT_OFF);
  __hip_bfloat16* Wvt = (__hip_bfloat16*)(ws + WVT_OFF);
  __hip_bfloat16* Wot = (__hip_bfloat16*)(ws + WOT_OFF);
  float*          F   = (float*)(ws + F_OFF);
  __hip_bfloat16* Qh  = (__hip_bfloat16*)(ws + QH_OFF);
  __hip_bfloat16* Kh  = (__hip_bfloat16*)(ws + KH_OFF);
  __hip_bfloat16* Vt  = (__hip_bfloat16*)(ws + VT_OFF);
  __hip_bfloat16* Ab  = (__hip_bfloat16*)(ws + AB_OFF);
  int* flag = (int*)d_out;   // scratch; overwritten by the final GEMM

  hipMemsetAsync(flag, 0, 4, stream);
  prep_kernel<<<10752, 256, 0, stream>>>(x, sinu, abias, Wq, Wk, Wv, Wo,
                                         Xb, F, Wqt, Wkt, Wvt, Wot, flag);

  qkv_kernel<<<dim3(3*HID/128, M_/128), 256, 0, stream>>>(
      Xb, Wqt, bq, bk, bv, F, Qh, Kh, Vt);

  flash_kernel<<<dim3(512), 256, 0, stream>>>(Qh, Kh, Vt, abias, flag, Ab);

  gemm_o64<<<dim3(HID/64, M_/128), 256, 0, stream>>>(Ab, Wot, (float*)d_out);
}

// Round 12
// 212.043 us; speedup vs baseline: 1.3691x; 1.0301x over previous
//
#include <hip/hip_runtime.h>
#include <hip/hip_bf16.h>

#define H_   16
#define D_   64
#define HID  1024
#define S_   2048
#define B_   2
#define M_   (B_*S_)
#define ROT  32
#define LOG2E 1.44269504088896341f
#define QSCALE (0.125f * LOG2E)

typedef __bf16 bf16x8 __attribute__((ext_vector_type(8)));
typedef float  f32x4  __attribute__((ext_vector_type(4)));

// ---- workspace layout (bytes) — round-5 proven map, no overlays ----
#define XB_OFF   0u                       // Xb bf16 [4096][1024]           8 MiB
#define WQT_OFF  (8u<<20)                 // Wq^T bf16 (QKV contiguous)     2 MiB
#define WKT_OFF  (10u<<20)
#define WVT_OFF  (12u<<20)
#define WOT_OFF  (14u<<20)
#define F_OFF    (16u<<20)                // rotary factors f32 [B][S][32]  512 KiB
#define QH_OFF   ((16u<<20) + (1u<<19))   // Q bf16 [B][H][S][D]            8 MiB
#define KH_OFF   (QH_OFF + (8u<<20))      // K bf16 [B][H][S][D]            8 MiB
#define VT_OFF   (KH_OFF + (8u<<20))      // V bf16 [B][H][D][S] (k-permuted tiles) 8 MiB
#define AB_OFF   (VT_OFF + (8u<<20))      // attn out bf16 [4096][1024]     8 MiB

__device__ __forceinline__ float fexp2(float x) {
#if __has_builtin(__builtin_amdgcn_exp2f)
  return __builtin_amdgcn_exp2f(x);
#else
  return __expf(x * 0.69314718055994531f);
#endif
}

__device__ __forceinline__ unsigned pk2(float a, float b) {
  union { unsigned u; __bf16 h[2]; } w;
  w.h[0] = (__bf16)a; w.h[1] = (__bf16)b;
  return w.u;
}

// ---------------- fused prep: convx | rotf | wtrans | biaschk ----------------
// flat grid: [0,4096) convx, [4096,4608) rotf, [4608,8704) wtrans, [8704,10752) biaschk
__global__ __launch_bounds__(256) void prep_kernel(const float* __restrict__ x,
                                                   const float* __restrict__ sinu,
                                                   const float* __restrict__ abias,
                                                   const float* __restrict__ W0, const float* __restrict__ W1,
                                                   const float* __restrict__ W2, const float* __restrict__ W3,
                                                   __hip_bfloat16* __restrict__ xb,
                                                   float* __restrict__ F,
                                                   __hip_bfloat16* __restrict__ T0, __hip_bfloat16* __restrict__ T1,
                                                   __hip_bfloat16* __restrict__ T2, __hip_bfloat16* __restrict__ T3,
                                                   int* __restrict__ flag) {
  __shared__ float tile[32][33];
  int idx = blockIdx.x;
  int tid = threadIdx.x;
  if (idx < 4096) {                       // ---- convx: x f32 -> bf16
    int i = (idx * 256 + tid) * 4;
    float4 v = *(const float4*)(x + i);
    union { __hip_bfloat16 h[4]; uint2 u; } o;
    o.h[0] = __float2bfloat16(v.x);
    o.h[1] = __float2bfloat16(v.y);
    o.h[2] = __float2bfloat16(v.z);
    o.h[3] = __float2bfloat16(v.w);
    *(uint2*)(xb + i) = o.u;
  } else if (idx < 4608) {                // ---- rotf: F = cos + (d odd ? sin : -sin)
    int i = (idx - 4096) * 256 + tid;
    int d  = i & (ROT-1);
    int bs = i >> 5;
    int s  = bs & (S_-1);
    int b  = bs >> 11;
    float sn = sinu[(((size_t)b*2 + 0)*S_ + s)*ROT + d];
    float cs = sinu[(((size_t)b*2 + 1)*S_ + s)*ROT + d];
    F[i] = cs + ((d & 1) ? sn : -sn);
  } else if (idx < 8704) {                // ---- wtrans: W[k][n] f32 -> Wt[n][k] bf16
    int widx = idx - 4608;
    int z    = widx >> 10;
    int rem  = widx & 1023;
    const float* W = (z==0) ? W0 : (z==1) ? W1 : (z==2) ? W2 : W3;
    __hip_bfloat16* T = (z==0) ? T0 : (z==1) ? T1 : (z==2) ? T2 : T3;
    int bx = (rem & 31) * 32;
    int by = (rem >> 5) * 32;
    int tx = tid & 31, ty = tid >> 5;
    #pragma unroll
    for (int i = 0; i < 4; i++)
      tile[ty + i*8][tx] = W[(size_t)(by + ty + i*8)*HID + bx + tx];
    __syncthreads();
    #pragma unroll
    for (int i = 0; i < 4; i++)
      T[(size_t)(bx + ty + i*8)*HID + by + tx] = __float2bfloat16(tile[tx][ty + i*8]);
  } else {                                // ---- biaschk: OR all bias bits
    size_t i = ((size_t)(idx - 8704) * 256 + tid) * 16;
    const uint4* p = (const uint4*)(abias + i);
    unsigned acc = 0;
    #pragma unroll
    for (int j = 0; j < 4; j++) {
      uint4 u = p[j];
      acc |= u.x | u.y | u.z | u.w;
    }
    if (acc) *flag = 1;
  }
}

// ---------------- m97-style 128x128 GEMM, fused QKV epilogue (round-6, proven) ----------------
__global__ __launch_bounds__(256) void qkv_kernel(const __hip_bfloat16* __restrict__ A,
                                                  const __hip_bfloat16* __restrict__ Bt,
                                                  const float* __restrict__ bq,
                                                  const float* __restrict__ bk,
                                                  const float* __restrict__ bv,
                                                  const float* __restrict__ F,
                                                  __hip_bfloat16* __restrict__ Qh,
                                                  __hip_bfloat16* __restrict__ Kh,
                                                  __hip_bfloat16* __restrict__ Vt) {
  __shared__ __align__(16) __bf16 Asm[2][128*32];
  __shared__ __align__(16) __bf16 Bsm[2][128*32];
  int tid  = threadIdx.x;
  int lane = tid & 63;
  int wv   = tid >> 6;
  int lr   = lane & 15;
  int qd   = lane >> 4;
  int row0 = blockIdx.y * 128;
  int col0 = blockIdx.x * 128;
  int wrow = (wv >> 1) * 64;
  int wcol = (wv & 1) * 64;

  int cg = ((tid & 3) ^ ((tid >> 2) & 3)) * 8;
  const __bf16* Ag = (const __bf16*)A  + (size_t)(row0 + (tid >> 2)) * HID + cg;
  const __bf16* Bg = (const __bf16*)Bt + (size_t)(col0 + (tid >> 2)) * HID + cg;

  f32x4 acc[4][4] = {};

  auto stage = [&](int buf, int k0) {
    __builtin_amdgcn_global_load_lds(Ag + k0,                  &Asm[buf][wv*512],        16, 0, 0);
    __builtin_amdgcn_global_load_lds(Ag + (size_t)64*HID + k0, &Asm[buf][2048 + wv*512], 16, 0, 0);
    __builtin_amdgcn_global_load_lds(Bg + k0,                  &Bsm[buf][wv*512],        16, 0, 0);
    __builtin_amdgcn_global_load_lds(Bg + (size_t)64*HID + k0, &Bsm[buf][2048 + wv*512], 16, 0, 0);
  };

  stage(0, 0);
  int buf = 0;
  for (int k0 = 0; k0 < HID; k0 += 32, buf ^= 1) {
    __syncthreads();
    if (k0 + 32 < HID) stage(buf ^ 1, k0 + 32);
    const __bf16* As = &Asm[buf][0];
    const __bf16* Bs = &Bsm[buf][0];
    bf16x8 a[4], b[4];
    #pragma unroll
    for (int i = 0; i < 4; i++) {
      int row = wrow + i*16 + lr;
      a[i] = *(const bf16x8*)(As + row*32 + ((qd ^ (row & 3)) * 8));
    }
    #pragma unroll
    for (int t = 0; t < 4; t++) {
      int row = wcol + t*16 + lr;
      b[t] = *(const bf16x8*)(Bs + row*32 + ((qd ^ (row & 3)) * 8));
    }
    #pragma unroll
    for (int i = 0; i < 4; i++)
      #pragma unroll
      for (int t = 0; t < 4; t++)
        acc[i][t] = __builtin_amdgcn_mfma_f32_16x16x32_bf16(a[i], b[t], acc[i][t], 0, 0, 0);
  }

  int proj = col0 >> 10;
  int nb   = (col0 & 1023) + wcol;
  const float* bias = (proj == 0) ? bq : ((proj == 1) ? bk : bv);
  #pragma unroll
  for (int i = 0; i < 4; i++) {
    #pragma unroll
    for (int t = 0; t < 4; t++) {
      int nl = nb + t*16 + lr;
      int h  = nl >> 6, d = nl & 63;
      if (proj == 2) {
        int m0 = row0 + wrow + i*16 + qd*4;
        int b2 = m0 >> 11, s0 = m0 & (S_-1);
        union { uint2 u; __bf16 hh[4]; } w;
        #pragma unroll
        for (int r = 0; r < 4; r++)
          w.hh[r] = (__bf16)(acc[i][t][r] + bias[nl]);
        // k-permuted store within each 64-wide s-tile: position 8m+j holds
        // k = 4m + (j&3) + 16*(j>>2)  (per 32-half). This makes the flash PV
        // B-operand equal to the lane's own packed scores (no P LDS round-trip).
        int pos = (s0 & ~31) | ((s0 & 12) << 1) | ((s0 >> 2) & 4);
        *(uint2*)((__bf16*)Vt + ((size_t)(b2*H_ + h)*D_ + d)*S_ + pos) = w.u;
      } else {
        __hip_bfloat16* dst = (proj == 0) ? Qh : Kh;
        #pragma unroll
        for (int r = 0; r < 4; r++) {
          int m = row0 + wrow + i*16 + qd*4 + r;
          int b2 = m >> 11, s = m & (S_-1);
          float v = acc[i][t][r] + bias[nl];
          if (d < ROT) v *= F[(size_t)(b2*S_ + s)*ROT + d];
          if (proj == 0) v *= QSCALE;
          dst[((size_t)(b2*H_ + h)*S_ + s)*D_ + d] = __float2bfloat16(v);
        }
      }
    }
  }
}

// ---------------- out-proj GEMM: 128x64 tiles, BK=64 (16 MFMA per barrier-pair) ----------------
// Round 12: old BK=32 loop issued only 8 MFMA per barrier-pair per wave (half of qkv's
// density) across 32 drain events. BK=64 stages the same total bytes in 16 iterations:
// 6 global_load_lds + 12 ds_read_b128 + 16 MFMA per iteration, halving barrier drains.
// LDS 48 KiB (2 blocks/CU, grid-capped at 2 anyway). Staging/read layout is flash's
// proven [rows][64] chunk-XOR pattern (cg8 = ((tid&7)^(row&7))*8, read (kk*4+qd)^(row&7)).
__global__ __launch_bounds__(256) void gemm_o64(const __hip_bfloat16* __restrict__ A,
                                                const __hip_bfloat16* __restrict__ Bt,
                                                float* __restrict__ outf) {
  __shared__ __align__(16) __bf16 Asm[2][128*64];
  __shared__ __align__(16) __bf16 Bsm[2][64*64];
  int tid  = threadIdx.x;
  int lane = tid & 63;
  int wv   = tid >> 6;
  int lr   = lane & 15;
  int qd   = lane >> 4;
  int row0 = blockIdx.y * 128;
  int col0 = blockIdx.x * 64;
  int rowb = tid >> 3;
  int cg8  = ((tid & 7) ^ (rowb & 7)) * 8;
  const __bf16* Ag = (const __bf16*)A  + (size_t)(row0 + rowb) * HID + cg8;
  const __bf16* Bg = (const __bf16*)Bt + (size_t)(col0 + rowb) * HID + cg8;

  f32x4 acc[2][4] = {};
  auto stage = [&](int buf, int k0) {
    __builtin_amdgcn_global_load_lds(Ag + k0,                  &Asm[buf][wv*512],        16, 0, 0);
    __builtin_amdgcn_global_load_lds(Ag + (size_t)32*HID + k0, &Asm[buf][2048 + wv*512], 16, 0, 0);
    __builtin_amdgcn_global_load_lds(Ag + (size_t)64*HID + k0, &Asm[buf][4096 + wv*512], 16, 0, 0);
    __builtin_amdgcn_global_load_lds(Ag + (size_t)96*HID + k0, &Asm[buf][6144 + wv*512], 16, 0, 0);
    __builtin_amdgcn_global_load_lds(Bg + k0,                  &Bsm[buf][wv*512],        16, 0, 0);
    __builtin_amdgcn_global_load_lds(Bg + (size_t)32*HID + k0, &Bsm[buf][2048 + wv*512], 16, 0, 0);
  };
  stage(0, 0);
  int buf = 0;
  for (int k0 = 0; k0 < HID; k0 += 64, buf ^= 1) {
    __syncthreads();
    if (k0 + 64 < HID) stage(buf ^ 1, k0 + 64);
    const __bf16* As = &Asm[buf][0];
    const __bf16* Bs = &Bsm[buf][0];
    bf16x8 a[2][2], b[4][2];
    #pragma unroll
    for (int i = 0; i < 2; i++) {
      int row = wv*32 + i*16 + lr;
      const __bf16* Ar = As + row*64;
      int sw = row & 7;
      a[i][0] = *(const bf16x8*)(Ar + ((qd       ^ sw) * 8));
      a[i][1] = *(const bf16x8*)(Ar + (((4 + qd) ^ sw) * 8));
    }
    #pragma unroll
    for (int t = 0; t < 4; t++) {
      int row = t*16 + lr;
      const __bf16* Br = Bs + row*64;
      int sw = row & 7;
      b[t][0] = *(const bf16x8*)(Br + ((qd       ^ sw) * 8));
      b[t][1] = *(const bf16x8*)(Br + (((4 + qd) ^ sw) * 8));
    }
    #pragma unroll
    for (int kk = 0; kk < 2; kk++)
      #pragma unroll
      for (int i = 0; i < 2; i++)
        #pragma unroll
        for (int t = 0; t < 4; t++)
          acc[i][t] = __builtin_amdgcn_mfma_f32_16x16x32_bf16(a[i][kk], b[t][kk], acc[i][t], 0, 0, 0);
  }
  #pragma unroll
  for (int i = 0; i < 2; i++)
    #pragma unroll
    for (int t = 0; t < 4; t++)
      #pragma unroll
      for (int r = 0; r < 4; r++) {
        int m = row0 + wv*32 + i*16 + qd*4 + r;
        int n = col0 + t*16 + lr;
        outf[(size_t)m*HID + n] = acc[i][t][r];
      }
}

// ---------------- flash attention: in-register P + one-behind PV (round-6, proven) ----------------
// Swapped QK^T leaves lane (lr,qd) holding P[q=lr][k=16c+4qd+r]. Vt's column order is
// permuted (position 8m+j holds k=4m+(j&3)+16*(j>>2) per 32-half), so the PV B-operand
// is the lane's own exp'd scores packed to bf16 — no P LDS, no cross-lane traffic.
// PV for tile i-1 is issued at the TOP of iteration i from persistent registers.
// lsum via MFMA — lacc = mfma(ones, pb, lacc) sums rows of P on the matrix pipe.
// V-frag ds_reads hoisted after PV(prev) so their latency drains under QK^T + exp.
__global__ __launch_bounds__(256) void flash_kernel(const __hip_bfloat16* __restrict__ Qh,
                                                    const __hip_bfloat16* __restrict__ Kh,
                                                    const __hip_bfloat16* __restrict__ Vt,
                                                    const float* __restrict__ abias,
                                                    const int* __restrict__ flag,
                                                    __hip_bfloat16* __restrict__ Ab) {
  __shared__ __align__(16) __bf16 Ksm[2][64*64];
  __shared__ __align__(16) __bf16 Vsm[2][64*64];
  int tid  = threadIdx.x;
  int lane = tid & 63;
  int wv   = tid >> 6;
  int lr   = lane & 15;
  int qd   = lane >> 4;
  int idx  = blockIdx.x;              // 0..511
  int xcd  = idx & 7;
  int slot = idx >> 3;                // 0..63
  int bh   = xcd * 4 + (slot >> 4);
  int qblk = slot & 15;
  int b  = bh >> 4;
  int h  = bh & 15;
  int q0 = qblk * 128 + wv * 32;

  const __bf16* Kbase = (const __bf16*)Kh + (size_t)bh*S_*D_;
  const __bf16* Vbase = (const __bf16*)Vt + (size_t)bh*D_*S_;

  const __bf16* Qp = (const __bf16*)Qh + ((size_t)bh*S_ + q0 + lr)*D_ + qd*8;
  bf16x8 qa00 = *(const bf16x8*)(Qp);
  bf16x8 qa01 = *(const bf16x8*)(Qp + 32);
  bf16x8 qa10 = *(const bf16x8*)(Qp + 16*D_);
  bf16x8 qa11 = *(const bf16x8*)(Qp + 16*D_ + 32);

  int hasbias = *flag;
  const float* bp0 = abias + (size_t)b*S_*S_ + (size_t)(q0 + lr)*S_;
  const float* bp1 = bp0 + (size_t)16*S_;

  int rowb = tid >> 3;
  int cg8  = ((tid & 7) ^ (rowb & 7)) * 8;

  auto stageKV = [&](int bf, int kt2) {
    __builtin_amdgcn_global_load_lds(Kbase + (size_t)(kt2 + rowb)*D_ + cg8,      &Ksm[bf][wv*512],        16, 0, 0);
    __builtin_amdgcn_global_load_lds(Kbase + (size_t)(kt2 + 32 + rowb)*D_ + cg8, &Ksm[bf][2048 + wv*512], 16, 0, 0);
    __builtin_amdgcn_global_load_lds(Vbase + (size_t)rowb*S_ + kt2 + cg8,        &Vsm[bf][wv*512],        16, 0, 0);
    __builtin_amdgcn_global_load_lds(Vbase + (size_t)(32 + rowb)*S_ + kt2 + cg8, &Vsm[bf][2048 + wv*512], 16, 0, 0);
  };

  f32x4 oacc0[4] = {}, oacc1[4] = {};
  f32x4 lacc0 = {}, lacc1 = {};       // row-sum accumulators (ones^T · P via MFMA)
  int sw = lr & 7;

  // all-ones bf16x8 A-operand for the row-sum MFMAs
  union { bf16x8 v; unsigned u[4]; } von;
  von.u[0] = von.u[1] = von.u[2] = von.u[3] = 0x3F803F80u;

  // persistent pipeline registers: P (bf16 fragments) and V frags of previous tile
  union Pu { bf16x8 v; unsigned u[4]; };
  Pu pb00 = {}, pb01 = {}, pb10 = {}, pb11 = {};
  bf16x8 vp0[4], vp1[4];

  stageKV(0, 0);
  int buf = 0;
  for (int kt = 0; kt < S_; kt += 64, buf ^= 1) {
    __syncthreads();                   // staged buf ready
    if (kt + 64 < S_) stageKV(buf ^ 1, kt + 64);

    // --- K frags for current tile (issue early; PV below is independent) ---
    bf16x8 kf0[4], kf1[4];
    #pragma unroll
    for (int c = 0; c < 4; c++) {
      const __bf16* Kr = &Ksm[buf][(c*16 + lr)*64];
      kf0[c] = *(const bf16x8*)(Kr + ((qd       ^ sw) * 8));
      kf1[c] = *(const bf16x8*)(Kr + (((4 + qd) ^ sw) * 8));
    }

    // --- PV for previous tile: all operands in registers, no waits ---
    if (kt > 0) {
      __builtin_amdgcn_s_setprio(1);
      #pragma unroll
      for (int t = 0; t < 4; t++) {
        oacc0[t] = __builtin_amdgcn_mfma_f32_16x16x32_bf16(vp0[t], pb00.v, oacc0[t], 0, 0, 0);
        oacc0[t] = __builtin_amdgcn_mfma_f32_16x16x32_bf16(vp1[t], pb01.v, oacc0[t], 0, 0, 0);
        oacc1[t] = __builtin_amdgcn_mfma_f32_16x16x32_bf16(vp0[t], pb10.v, oacc1[t], 0, 0, 0);
        oacc1[t] = __builtin_amdgcn_mfma_f32_16x16x32_bf16(vp1[t], pb11.v, oacc1[t], 0, 0, 0);
      }
      __builtin_amdgcn_s_setprio(0);
    }

    // --- V frags (k-permuted layout) into persistent registers: issued early so the
    //     ds_read latency drains under QK^T + exp (consumed next iteration) ---
    #pragma unroll
    for (int t = 0; t < 4; t++) {
      const __bf16* Vr = &Vsm[buf][(t*16 + lr)*64];
      vp0[t] = *(const bf16x8*)(Vr + ((qd       ^ sw) * 8));
      vp1[t] = *(const bf16x8*)(Vr + (((4 + qd) ^ sw) * 8));
    }

    // --- scores for current tile ---
    f32x4 s0[4], s1[4];
    __builtin_amdgcn_s_setprio(1);
    #pragma unroll
    for (int c = 0; c < 4; c++) {
      f32x4 z = {};
      z     = __builtin_amdgcn_mfma_f32_16x16x32_bf16(kf0[c], qa00, z, 0, 0, 0);
      s0[c] = __builtin_amdgcn_mfma_f32_16x16x32_bf16(kf1[c], qa01, z, 0, 0, 0);
      f32x4 z2 = {};
      z2    = __builtin_amdgcn_mfma_f32_16x16x32_bf16(kf0[c], qa10, z2, 0, 0, 0);
      s1[c] = __builtin_amdgcn_mfma_f32_16x16x32_bf16(kf1[c], qa11, z2, 0, 0, 0);
    }
    __builtin_amdgcn_s_setprio(0);

    // --- bias (slow path only) ---
    if (hasbias) {
      #pragma unroll
      for (int c = 0; c < 4; c++) {
        float4 b0 = *(const float4*)(bp0 + kt + c*16 + qd*4);
        float4 b1 = *(const float4*)(bp1 + kt + c*16 + qd*4);
        s0[c][0] += b0.x*LOG2E; s0[c][1] += b0.y*LOG2E; s0[c][2] += b0.z*LOG2E; s0[c][3] += b0.w*LOG2E;
        s1[c][0] += b1.x*LOG2E; s1[c][1] += b1.y*LOG2E; s1[c][2] += b1.z*LOG2E; s1[c][3] += b1.w*LOG2E;
      }
    }

    // --- exp2 + pack into persistent PV B-fragments (consumed next iter) ---
    #pragma unroll
    for (int c = 0; c < 2; c++) {
      pb00.u[2*c]   = pk2(fexp2(s0[c][0]), fexp2(s0[c][1]));
      pb00.u[2*c+1] = pk2(fexp2(s0[c][2]), fexp2(s0[c][3]));
      pb10.u[2*c]   = pk2(fexp2(s1[c][0]), fexp2(s1[c][1]));
      pb10.u[2*c+1] = pk2(fexp2(s1[c][2]), fexp2(s1[c][3]));
    }
    #pragma unroll
    for (int c = 2; c < 4; c++) {
      pb01.u[2*(c-2)]   = pk2(fexp2(s0[c][0]), fexp2(s0[c][1]));
      pb01.u[2*(c-2)+1] = pk2(fexp2(s0[c][2]), fexp2(s0[c][3]));
      pb11.u[2*(c-2)]   = pk2(fexp2(s1[c][0]), fexp2(s1[c][1]));
      pb11.u[2*(c-2)+1] = pk2(fexp2(s1[c][2]), fexp2(s1[c][3]));
    }

    // --- row sums on the matrix pipe: lacc += ones^T · P(cur) ---
    lacc0 = __builtin_amdgcn_mfma_f32_16x16x32_bf16(von.v, pb00.v, lacc0, 0, 0, 0);
    lacc0 = __builtin_amdgcn_mfma_f32_16x16x32_bf16(von.v, pb01.v, lacc0, 0, 0, 0);
    lacc1 = __builtin_amdgcn_mfma_f32_16x16x32_bf16(von.v, pb10.v, lacc1, 0, 0, 0);
    lacc1 = __builtin_amdgcn_mfma_f32_16x16x32_bf16(von.v, pb11.v, lacc1, 0, 0, 0);
  }

  // --- final PV for the last tile (all operands in registers) ---
  __builtin_amdgcn_s_setprio(1);
  #pragma unroll
  for (int t = 0; t < 4; t++) {
    oacc0[t] = __builtin_amdgcn_mfma_f32_16x16x32_bf16(vp0[t], pb00.v, oacc0[t], 0, 0, 0);
    oacc0[t] = __builtin_amdgcn_mfma_f32_16x16x32_bf16(vp1[t], pb01.v, oacc0[t], 0, 0, 0);
    oacc1[t] = __builtin_amdgcn_mfma_f32_16x16x32_bf16(vp0[t], pb10.v, oacc1[t], 0, 0, 0);
    oacc1[t] = __builtin_amdgcn_mfma_f32_16x16x32_bf16(vp1[t], pb11.v, oacc1[t], 0, 0, 0);
  }
  __builtin_amdgcn_s_setprio(0);

  // lacc[r] holds the full row sum for q-row lr (replicated across r and qd)
  float inv0 = 1.0f / lacc0[0];
  float inv1 = 1.0f / lacc1[0];
  size_t ro0 = ((size_t)(b*S_ + q0 + lr))*HID + h*D_;
  size_t ro1 = ((size_t)(b*S_ + q0 + 16 + lr))*HID + h*D_;
  #pragma unroll
  for (int t = 0; t < 4; t++) {
    union { uint2 u; __bf16 hh[4]; } w0, w1;
    #pragma unroll
    for (int r = 0; r < 4; r++) {
      w0.hh[r] = (__bf16)(oacc0[t][r]*inv0);
      w1.hh[r] = (__bf16)(oacc1[t][r]*inv1);
    }
    *(uint2*)((__bf16*)Ab + ro0 + t*16 + qd*4) = w0.u;
    *(uint2*)((__bf16*)Ab + ro1 + t*16 + qd*4) = w1.u;
  }
}

extern "C" void kernel_launch(void* const* d_in, const int* in_sizes, int n_in,
                              void* d_out, int out_size, void* d_ws, size_t ws_size,
                              hipStream_t stream) {
  (void)in_sizes; (void)n_in; (void)out_size; (void)ws_size;
  const float* x     = (const float*)d_in[0];
  const float* sinu  = (const float*)d_in[1];
  const float* abias = (const float*)d_in[2];
  const float* Wq    = (const float*)d_in[3];
  const float* bq    = (const float*)d_in[4];
  const float* Wk    = (const float*)d_in[5];
  const float* bk    = (const float*)d_in[6];
  const float* Wv    = (const float*)d_in[7];
  const float* bv    = (const float*)d_in[8];
  const float* Wo    = (const float*)d_in[9];

  char* ws = (char*)d_ws;
  __hip_bfloat16* Xb  = (__hip_bfloat16*)(ws + XB_OFF);
  __hip_bfloat16* Wqt = (__hip_bfloat16*)(ws + WQT_OFF);
  __hip_bfloat16* Wkt = (__hip_bfloat16*)(ws + WKT_OFF);
  __hip_bfloat16* Wvt = (__hip_bfloat16*)(ws + WVT_OFF);
  __hip_bfloat16* Wot = (__hip_bfloat16*)(ws + WOT_OFF);
  float*          F   = (float*)(ws + F_OFF);
  __hip_bfloat16* Qh  = (__hip_bfloat16*)(ws + QH_OFF);
  __hip_bfloat16* Kh  = (__hip_bfloat16*)(ws + KH_OFF);
  __hip_bfloat16* Vt  = (__hip_bfloat16*)(ws + VT_OFF);
  __hip_bfloat16* Ab  = (__hip_bfloat16*)(ws + AB_OFF);
  int* flag = (int*)d_out;   // scratch; overwritten by the final GEMM

  hipMemsetAsync(flag, 0, 4, stream);
  prep_kernel<<<10752, 256, 0, stream>>>(x, sinu, abias, Wq, Wk, Wv, Wo,
                                         Xb, F, Wqt, Wkt, Wvt, Wot, flag);

  qkv_kernel<<<dim3(3*HID/128, M_/128), 256, 0, stream>>>(
      Xb, Wqt, bq, bk, bv, F, Qh, Kh, Vt);

  flash_kernel<<<dim3(512), 256, 0, stream>>>(Qh, Kh, Vt, abias, flag, Ab);

  gemm_o64<<<dim3(HID/64, M_/128), 256, 0, stream>>>(Ab, Wot, (float*)d_out);
}